// Round 6
// baseline (3435.427 us; speedup 1.0000x reference)
//
#include <hip/hip_runtime.h>
#include <math.h>

#define BB 32
#define NN 1024
#define BN (BB*NN)
#define GRID_LOOP 256
#define XPAD 132

__device__ __forceinline__ float sigmoidf_(float v) { return 1.0f / (1.0f + expf(-v)); }
__device__ __forceinline__ unsigned f2bf(float f) {           // round-to-nearest-even bf16 bits
  unsigned u = __float_as_uint(f);
  return (u + 0x7fffu + ((u >> 16) & 1u)) >> 16;
}

// ---------------- init: zero h, c, barrier words ----------------
__global__ void k_init(float* __restrict__ h, float* __restrict__ c, int* __restrict__ bar) {
  int i = blockIdx.x * 256 + threadIdx.x;   // 128 x 256 = 32768
  h[i] = 0.0f; c[i] = 0.0f;
  if (i < 2) bar[i] = 0;
}

// ---------------- embedding: emb[row][256] fp32 + embh[row][128] packed bf16x2 ----------------
__global__ void k_emb(const int* __restrict__ xint, const float* __restrict__ xyz,
                      const float* __restrict__ am, const float* __restrict__ el,
                      const float* __restrict__ po, const float* __restrict__ xw,
                      const float* __restrict__ xb, float* __restrict__ emb,
                      unsigned* __restrict__ embh) {
  __shared__ float sv[256];
  int row = blockIdx.x;
  int d = threadIdx.x;
  int i0 = xint[row*3+0], i1 = xint[row*3+1], i2 = xint[row*3+2];
  float v;
  if (d < 28)        v = am[i0*28 + d];
  else if (d < 56)   v = el[i1*28 + (d-28)];
  else if (d < 84)   v = po[i2*28 + (d-56)];
  else {
    int o = d - 84;
    float x0 = xyz[row*3+0], x1 = xyz[row*3+1], x2 = xyz[row*3+2];
    v = fmaxf(xw[o*3+0]*x0 + xw[o*3+1]*x1 + xw[o*3+2]*x2 + xb[o], 0.0f);
  }
  emb[(size_t)row*256 + d] = v;
  sv[d] = v;
  __syncthreads();
  if (d < 128) {
    unsigned u = (f2bf(sv[d*2+1]) << 16) | f2bf(sv[d*2]);
    embh[(size_t)row*128 + d] = u;
  }
}

// ---------------- transpose+quantize weights: wt2[k2][j] = pack(bf16 w[2k2][j], bf16 w[2k2+1][j]) ----------------
__global__ __launch_bounds__(256) void k_wt(const float* __restrict__ w_ih,
        const float* __restrict__ w_hh, unsigned* __restrict__ wt2) {
  __shared__ float t[32][33];
  int jt = blockIdx.x * 32, kt = blockIdx.y * 32;
  int tx = threadIdx.x & 31, ty = threadIdx.x >> 5;   // ty 0..7
#pragma unroll
  for (int i = 0; i < 4; i++) {
    int j = jt + ty + i*8;
    int k = kt + tx;
    float v = (k < 2048) ? w_ih[(size_t)j*2048 + k] : w_hh[(size_t)j*1024 + (k - 2048)];
    t[ty + i*8][tx] = v;                              // t[j_local][k_local]
  }
  __syncthreads();
#pragma unroll
  for (int i = 0; i < 2; i++) {
    int kl2 = ty + i*8;                               // 0..15
    float lo = t[tx][kl2*2], hi = t[tx][kl2*2+1];
    unsigned u = (f2bf(hi) << 16) | f2bf(lo);
    wt2[(size_t)((kt >> 1) + kl2)*4096 + jt + tx] = u;
  }
}

// ---------------- Wc partials: wcp[och][k][d] ----------------
__global__ void k_wc1(const float* __restrict__ up_w, const float* __restrict__ att1w,
                      float* __restrict__ wcp) {
  int k = blockIdx.x;       // 128
  int och = blockIdx.y;     // 8
  int d = threadIdx.x;      // 256
  __shared__ float s[128];
  int o0 = och*128;
  if (d < 128) s[d] = att1w[(size_t)k*2048 + 1024 + o0 + d];
  __syncthreads();
  float acc = 0.0f;
#pragma unroll 8
  for (int oi = 0; oi < 128; oi++) acc += up_w[(size_t)(o0+oi)*256 + d] * s[oi];
  wcp[((size_t)och*128 + k)*256 + d] = acc;
}

__global__ void k_wc2(const float* __restrict__ wcp, float* __restrict__ wc) {
  int k = blockIdx.x, d = threadIdx.x;
  float s = 0.0f;
#pragma unroll
  for (int p = 0; p < 8; p++) s += wcp[((size_t)p*128 + k)*256 + d];
  wc[k*256 + d] = s;
}

// ---------------- bc[k] = sum_o up_b[o] * att1_w[k][1024+o] ----------------
__global__ void k_bc(const float* __restrict__ up_b, const float* __restrict__ att1w,
                     float* __restrict__ bc) {
  int k = blockIdx.x;   // 128 blocks x 64 threads
  int t = threadIdx.x;
  float acc = 0.0f;
#pragma unroll
  for (int i = 0; i < 4; i++) {
    int o = i*256 + t*4;
    float4 a4 = *(const float4*)(att1w + (size_t)k*2048 + 1024 + o);
    float4 b4 = *(const float4*)(up_b + o);
    acc += a4.x*b4.x + a4.y*b4.y + a4.z*b4.z + a4.w*b4.w;
  }
#pragma unroll
  for (int m = 32; m >= 1; m >>= 1) acc += __shfl_xor(acc, m, 64);
  if (t == 0) bc[k] = acc;
}

// ---------------- fp32 GEMM 32x128 tile, BK=32: xa = emb @ wc^T + bc ----------------
__global__ __launch_bounds__(256) void k_gemm32(const float* __restrict__ A,
        const float* __restrict__ W, const float* __restrict__ bias,
        float* __restrict__ C) {
  __shared__ float As[32][33];
  __shared__ float Bs[32][132];
  const int m0 = blockIdx.x * 32;
  const int tid = threadIdx.x;
  const int tx = tid & 15, ty = tid >> 4;
  float acc[2][8];
#pragma unroll
  for (int i = 0; i < 2; i++)
#pragma unroll
    for (int j = 0; j < 8; j++) acc[i][j] = 0.0f;

  for (int kt = 0; kt < 256; kt += 32) {
    {
      int r = tid >> 3;               // 0..31
      int kq = (tid & 7) * 4;         // 0..28
      float4 a4 = *(const float4*)(A + (size_t)(m0 + r)*256 + kt + kq);
      As[kq+0][r] = a4.x; As[kq+1][r] = a4.y; As[kq+2][r] = a4.z; As[kq+3][r] = a4.w;
    }
#pragma unroll
    for (int i = 0; i < 4; i++) {
      int s = tid + i*256;            // 0..1023
      int n = s >> 3;                 // 0..127
      int kq = (s & 7) * 4;
      float4 b4 = *(const float4*)(W + (size_t)n*256 + kt + kq);
      Bs[kq+0][n] = b4.x; Bs[kq+1][n] = b4.y; Bs[kq+2][n] = b4.z; Bs[kq+3][n] = b4.w;
    }
    __syncthreads();
#pragma unroll
    for (int kk = 0; kk < 32; kk++) {
      float a0 = As[kk][ty*2], a1 = As[kk][ty*2+1];
      float4 b0 = *(const float4*)&Bs[kk][tx*4];
      float4 b1 = *(const float4*)&Bs[kk][64 + tx*4];
      float bv[8] = {b0.x,b0.y,b0.z,b0.w,b1.x,b1.y,b1.z,b1.w};
#pragma unroll
      for (int j = 0; j < 8; j++) { acc[0][j] += a0*bv[j]; acc[1][j] += a1*bv[j]; }
    }
    __syncthreads();
  }
#pragma unroll
  for (int i = 0; i < 2; i++) {
    int row = m0 + ty*2 + i;
#pragma unroll
    for (int ch = 0; ch < 2; ch++) {
      int col = ch*64 + tx*4;
      float4 o;
      o.x = acc[i][ch*4+0] + bias[col+0];
      o.y = acc[i][ch*4+1] + bias[col+1];
      o.z = acc[i][ch*4+2] + bias[col+2];
      o.w = acc[i][ch*4+3] + bias[col+3];
      *(float4*)(C + (size_t)row*128 + col) = o;
    }
  }
}

// ---------------- persistent loop kernel (regular launch, manual grid barrier) ----------------
__global__ __launch_bounds__(256) void k_loop(
    const unsigned* __restrict__ wt2, const unsigned* __restrict__ embh,
    const float* __restrict__ xa, const float* __restrict__ up_w,
    const float* __restrict__ up_b, const float* __restrict__ b_ih,
    const float* __restrict__ b_hh, const float* __restrict__ att1w,
    const float* __restrict__ att1b, const float* __restrict__ att2w,
    const float* __restrict__ att2b, const float* __restrict__ en_w,
    const float* __restrict__ en_b,
    float* __restrict__ G, float* __restrict__ P, float* __restrict__ h,
    float* __restrict__ c, float* __restrict__ rap, float* __restrict__ lg,
    float* __restrict__ pp, float* __restrict__ outp, int* __restrict__ bar)
{
  __shared__ __align__(16) float sm[32*XPAD];   // 16.9 KB, reused by every phase
  const int tid = threadIdx.x;
  int lsense = 0;

  // sense-reversing grid barrier; all GRID_LOOP blocks are co-resident by capacity.
  auto GBAR = [&]() {
    __syncthreads();
    if (tid == 0) {
      int s = lsense ^ 1;
      lsense = s;
      if (__hip_atomic_fetch_add(&bar[0], 1, __ATOMIC_ACQ_REL, __HIP_MEMORY_SCOPE_AGENT) == GRID_LOOP - 1) {
        __hip_atomic_store(&bar[0], 0, __ATOMIC_RELAXED, __HIP_MEMORY_SCOPE_AGENT);
        __hip_atomic_store(&bar[1], s, __ATOMIC_RELEASE, __HIP_MEMORY_SCOPE_AGENT);
      } else {
        while (__hip_atomic_load(&bar[1], __ATOMIC_ACQUIRE, __HIP_MEMORY_SCOPE_AGENT) != s)
          __builtin_amdgcn_s_sleep(2);
      }
    } else {
      lsense ^= 1;
    }
    __syncthreads();
  };

  // ---- phase: weighted pool of embh -> pp partials ----
  auto POOL = [&](bool use_lg) {
    for (int wb = blockIdx.x; wb < 128; wb += GRID_LOOP) {
      int b = wb >> 2, nch = wb & 3;
      float* ws = sm; float* red = sm + 256;
      if (use_lg) {
        float mx = -1e30f;
#pragma unroll
        for (int i = 0; i < 4; i++) mx = fmaxf(mx, lg[b*1024 + tid + i*256]);
        red[tid] = mx; __syncthreads();
        for (int s = 128; s > 0; s >>= 1) { if (tid < s) red[tid] = fmaxf(red[tid], red[tid+s]); __syncthreads(); }
        float m = red[0]; __syncthreads();
        float sum = 0.0f;
#pragma unroll
        for (int i = 0; i < 4; i++) sum += expf(lg[b*1024 + tid + i*256] - m);
        red[tid] = sum; __syncthreads();
        for (int s = 128; s > 0; s >>= 1) { if (tid < s) red[tid] += red[tid+s]; __syncthreads(); }
        float inv = 1.0f / red[0];
        __syncthreads();
        ws[tid] = expf(lg[b*1024 + nch*256 + tid] - m) * inv;
      } else {
        ws[tid] = 1.0f;
      }
      __syncthreads();
      int pu = tid & 127, ng = tid >> 7;
      const unsigned* eb = embh + (size_t)(b*1024 + nch*256 + ng*128)*128 + pu;
      float a0 = 0.0f, a1 = 0.0f;
#pragma unroll 4
      for (int n = 0; n < 128; n++) {
        unsigned u = eb[(size_t)n*128];
        float w = ws[ng*128 + n];
        a0 += w * __uint_as_float(u << 16);
        a1 += w * __uint_as_float(u & 0xffff0000u);
      }
      int p = nch*2 + ng;
      pp[((size_t)p*32 + b)*256 + pu*2]     = a0;
      pp[((size_t)p*32 + b)*256 + pu*2 + 1] = a1;
      __syncthreads();
    }
  };

  // ---- phase: reduce pp -> pe (in LDS) ; P = pe @ up_w^T + up_b ----
  auto PGEMM = [&](float scale) {
    for (int wb = blockIdx.x; wb < 128; wb += GRID_LOOP) {
      int b = wb >> 2, oc = wb & 3;
      float s = 0.0f;
#pragma unroll
      for (int p = 0; p < 8; p++) s += pp[((size_t)p*32 + b)*256 + tid];
      sm[tid] = s * scale;
      __syncthreads();
      int o = oc*256 + tid;
      const float* wr = up_w + (size_t)o*256;
      float acc = up_b[o];
#pragma unroll 8
      for (int d = 0; d < 256; d += 4) {
        float4 w4 = *(const float4*)(wr + d);
        acc += w4.x*sm[d] + w4.y*sm[d+1] + w4.z*sm[d+2] + w4.w*sm[d+3];
      }
      P[(size_t)b*1024 + o] = acc;
      __syncthreads();
    }
  };

  // ---- phase: full-K gates -> final biased G[b][j]. 128 items x 32 j ----
  auto GATES = [&]() {
    for (int wb = blockIdx.x; wb < 128; wb += GRID_LOOP) {
      int j0 = wb * 32;
      int jg = tid & 7, bg = tid >> 3;      // 8 j-groups x 32 b
      float acc[4] = {0.0f, 0.0f, 0.0f, 0.0f};
      for (int ks = 0; ks < 24; ks++) {
        const float* src; int soff;
        int kglob = ks * 128;
        if (ks < 8)       { src = P; soff = kglob; }
        else if (ks < 16) { src = h; soff = kglob - 1024; }
        else              { src = h; soff = kglob - 2048; }
#pragma unroll
        for (int i = 0; i < 4; i++) {
          int s = tid + i*256;              // float4 idx 0..1023
          int b = s >> 5, k4 = s & 31;
          *(float4*)&sm[b*XPAD + k4*4] = *(const float4*)(src + b*1024 + soff + k4*4);
        }
        __syncthreads();
        const unsigned* wr = wt2 + (size_t)(ks*64)*4096 + j0 + jg*4;
        const float* xb = sm + bg*XPAD;
#pragma unroll 4
        for (int k2 = 0; k2 < 64; k2++) {
          uint4 u4 = *(const uint4*)(wr + (size_t)k2*4096);
          float x0 = xb[k2*2], x1 = xb[k2*2+1];
          acc[0] += __uint_as_float(u4.x << 16)*x0 + __uint_as_float(u4.x & 0xffff0000u)*x1;
          acc[1] += __uint_as_float(u4.y << 16)*x0 + __uint_as_float(u4.y & 0xffff0000u)*x1;
          acc[2] += __uint_as_float(u4.z << 16)*x0 + __uint_as_float(u4.z & 0xffff0000u)*x1;
          acc[3] += __uint_as_float(u4.w << 16)*x0 + __uint_as_float(u4.w & 0xffff0000u)*x1;
        }
        __syncthreads();
      }
#pragma unroll
      for (int ji = 0; ji < 4; ji++) {
        int j = j0 + jg*4 + ji;
        G[(size_t)bg*4096 + j] = acc[ji] + b_ih[j] + b_hh[j];
      }
      __syncthreads();
    }
  };

  // ---- phase: LSTM cell + ra partials per dch ----
  auto LSTM = [&](bool need_ra) {
    for (int wb = blockIdx.x; wb < 128; wb += GRID_LOOP) {
      int b = wb >> 2, dch = wb & 3;
      int d = dch*256 + tid;
      const float* Gb = G + (size_t)b*4096;
      float gi = Gb[d], gf = Gb[1024 + d], gg = Gb[2048 + d], go = Gb[3072 + d];
      size_t ci = (size_t)b*1024 + d;
      float cn = sigmoidf_(gf)*c[ci] + sigmoidf_(gi)*tanhf(gg);
      c[ci] = cn;
      float hn = sigmoidf_(go)*tanhf(cn);
      h[ci] = hn;
      sm[tid] = hn;
      __syncthreads();
      if (need_ra) {
        int k = tid >> 1, half = tid & 1;
        const float* wr = att1w + (size_t)k*2048 + dch*256 + half*128;
        float acc = 0.0f;
#pragma unroll 8
        for (int i = 0; i < 32; i++) {
          float4 w4 = *(const float4*)(wr + i*4);
          int dl = half*128 + i*4;
          acc += w4.x*sm[dl] + w4.y*sm[dl+1] + w4.z*sm[dl+2] + w4.w*sm[dl+3];
        }
        acc += __shfl_xor(acc, 1, 64);
        if (half == 0) rap[((size_t)dch*32 + b)*128 + k] = acc;
      }
      __syncthreads();
    }
  };

  // ---- phase: logits ----
  auto LOGITS = [&]() {
    for (int wb = blockIdx.x; wb < 256; wb += GRID_LOOP) {
      int b = wb >> 3, nc = wb & 7;
      float* rb = sm; float* w2 = sm + 128;
      if (tid < 128) {
        float r = rap[(size_t)(0  + b)*128 + tid] + rap[(size_t)(32 + b)*128 + tid]
                + rap[(size_t)(64 + b)*128 + tid] + rap[(size_t)(96 + b)*128 + tid];
        rb[tid] = r + att1b[tid];
        w2[tid] = att2w[tid];
      }
      __syncthreads();
      int n = nc*128 + (tid >> 1);
      int half = (tid & 1) * 64;
      const float* xr = xa + ((size_t)b*1024 + n)*128 + half;
      float acc = 0.0f;
#pragma unroll
      for (int i = 0; i < 16; i++) {
        int kk = i*4;
        float4 v = *(const float4*)(xr + kk);
        int kg = half + kk;
        acc += fmaxf(v.x + rb[kg+0], 0.0f)*w2[kg+0]
             + fmaxf(v.y + rb[kg+1], 0.0f)*w2[kg+1]
             + fmaxf(v.z + rb[kg+2], 0.0f)*w2[kg+2]
             + fmaxf(v.w + rb[kg+3], 0.0f)*w2[kg+3];
      }
      acc += __shfl_xor(acc, 1, 64);
      if ((tid & 1) == 0) lg[(size_t)b*1024 + n] = acc + att2b[0];
      __syncthreads();
    }
  };

  // ---- phase: energy head ----
  auto OUT = [&]() {
    for (int wb = blockIdx.x; wb < 32; wb += GRID_LOOP) {
      float a = 0.0f;
#pragma unroll
      for (int i = 0; i < 4; i++) { int d = tid + i*256; a += c[(size_t)wb*1024 + d] * en_w[d]; }
      sm[tid] = a; __syncthreads();
      for (int s = 128; s > 0; s >>= 1) { if (tid < s) sm[tid] += sm[tid+s]; __syncthreads(); }
      if (tid == 0) outp[wb] = sm[0] + en_b[0];
      __syncthreads();
    }
  };

  POOL(false);
  GBAR();
  PGEMM(1.0f/1024.0f);
  GBAR();

  for (int step = 0; step < 6; ++step) {
    GATES();
    GBAR();
    LSTM(step < 5);
    GBAR();
    if (step < 5) {      // last step's attention output is unused
      LOGITS();
      GBAR();
      POOL(true);
      GBAR();
      PGEMM(1.0f);
      GBAR();
    }
  }
  OUT();
}

extern "C" void kernel_launch(void* const* d_in, const int* in_sizes, int n_in,
                              void* d_out, int out_size, void* d_ws, size_t ws_size,
                              hipStream_t stream) {
  const int*   x_int  = (const int*)d_in[0];
  const float* x_xyz  = (const float*)d_in[1];
  const float* am     = (const float*)d_in[2];
  const float* el     = (const float*)d_in[3];
  const float* po     = (const float*)d_in[4];
  const float* xyz_w  = (const float*)d_in[5];
  const float* xyz_b  = (const float*)d_in[6];
  const float* up_w   = (const float*)d_in[7];
  const float* up_b   = (const float*)d_in[8];
  const float* w_ih   = (const float*)d_in[9];
  const float* w_hh   = (const float*)d_in[10];
  const float* b_ih   = (const float*)d_in[11];
  const float* b_hh   = (const float*)d_in[12];
  const float* att1_w = (const float*)d_in[13];
  const float* att1_b = (const float*)d_in[14];
  const float* att2_w = (const float*)d_in[15];
  const float* att2_b = (const float*)d_in[16];
  const float* en_w   = (const float*)d_in[17];
  const float* en_b   = (const float*)d_in[18];
  float* out = (float*)d_out;

  char* ws = (char*)d_ws;
  size_t off = 0;
  auto alloc = [&](size_t bytes) { void* p = ws + off; off += (bytes + 255) & ~(size_t)255; return p; };
  float*    emb  = (float*)alloc((size_t)BN*256*4);       // 33.6 MB
  unsigned* embh = (unsigned*)alloc((size_t)BN*128*4);    // 16.8 MB (bf16x2)
  unsigned* wt2  = (unsigned*)alloc((size_t)1536*4096*4); // 25.2 MB
  float*    xa   = (float*)alloc((size_t)BN*128*4);       // 16.8 MB
  float*    wcp  = (float*)alloc((size_t)8*128*256*4);    // 1 MB
  float*    wc   = (float*)alloc((size_t)128*256*4);
  float*    bc   = (float*)alloc((size_t)128*4);
  float*    G    = (float*)alloc((size_t)32*4096*4);      // 512 KB
  float*    pp   = (float*)alloc((size_t)8*32*256*4);     // 256 KB
  float*    P    = (float*)alloc((size_t)32*1024*4);
  float*    h    = (float*)alloc((size_t)32*1024*4);
  float*    c    = (float*)alloc((size_t)32*1024*4);
  float*    rap  = (float*)alloc((size_t)4*32*128*4);
  float*    lg   = (float*)alloc((size_t)32*1024*4);
  int*      bar  = (int*)alloc(256);
  (void)ws_size; (void)in_sizes; (void)n_in; (void)out_size;

  k_init<<<128, 256, 0, stream>>>(h, c, bar);
  k_emb<<<BN, 256, 0, stream>>>(x_int, x_xyz, am, el, po, xyz_w, xyz_b, emb, embh);
  k_wt<<<dim3(128, 96), 256, 0, stream>>>(w_ih, w_hh, wt2);
  k_wc1<<<dim3(128, 8), 256, 0, stream>>>(up_w, att1_w, wcp);
  k_wc2<<<128, 256, 0, stream>>>(wcp, wc);
  k_bc<<<128, 64, 0, stream>>>(up_b, att1_w, bc);
  // xa = emb @ wc^T + bc   (M=32768, K=256, N=128)
  k_gemm32<<<BN/32, 256, 0, stream>>>(emb, wc, bc, xa);

  k_loop<<<GRID_LOOP, 256, 0, stream>>>(
      wt2, embh, xa, up_w, up_b, b_ih, b_hh, att1_w, att1_b,
      att2_w, att2_b, en_w, en_b,
      G, P, h, c, rap, lg, pp, out, bar);
}

// Round 7
// 3198.356 us; speedup vs baseline: 1.0741x; 1.0741x over previous
//
#include <hip/hip_runtime.h>
#include <math.h>

#define BB 32
#define NN 1024
#define BN (BB*NN)
#define GRID_LOOP 512
#define XPAD 132

__device__ __forceinline__ float sigmoidf_(float v) { return 1.0f / (1.0f + expf(-v)); }
__device__ __forceinline__ unsigned f2bf(float f) {           // round-to-nearest-even bf16 bits
  unsigned u = __float_as_uint(f);
  return (u + 0x7fffu + ((u >> 16) & 1u)) >> 16;
}

// ---------------- init: zero h, c, barrier flags ----------------
__global__ void k_init(float* __restrict__ h, float* __restrict__ c, int* __restrict__ bar) {
  int i = blockIdx.x * 256 + threadIdx.x;   // 128 x 256 = 32768
  h[i] = 0.0f; c[i] = 0.0f;
  if (i <= GRID_LOOP*32) bar[i] = 0;        // flags + release word
}

// ---------------- embedding: emb[row][256] fp32 + embh[row][128] packed bf16x2 ----------------
__global__ void k_emb(const int* __restrict__ xint, const float* __restrict__ xyz,
                      const float* __restrict__ am, const float* __restrict__ el,
                      const float* __restrict__ po, const float* __restrict__ xw,
                      const float* __restrict__ xb, float* __restrict__ emb,
                      unsigned* __restrict__ embh) {
  __shared__ float sv[256];
  int row = blockIdx.x;
  int d = threadIdx.x;
  int i0 = xint[row*3+0], i1 = xint[row*3+1], i2 = xint[row*3+2];
  float v;
  if (d < 28)        v = am[i0*28 + d];
  else if (d < 56)   v = el[i1*28 + (d-28)];
  else if (d < 84)   v = po[i2*28 + (d-56)];
  else {
    int o = d - 84;
    float x0 = xyz[row*3+0], x1 = xyz[row*3+1], x2 = xyz[row*3+2];
    v = fmaxf(xw[o*3+0]*x0 + xw[o*3+1]*x1 + xw[o*3+2]*x2 + xb[o], 0.0f);
  }
  emb[(size_t)row*256 + d] = v;
  sv[d] = v;
  __syncthreads();
  if (d < 128) {
    unsigned u = (f2bf(sv[d*2+1]) << 16) | f2bf(sv[d*2]);
    embh[(size_t)row*128 + d] = u;
  }
}

// ---------------- transpose+quantize weights: wt2[k2][j] = pack(bf16 w[2k2][j], bf16 w[2k2+1][j]) ----------------
__global__ __launch_bounds__(256) void k_wt(const float* __restrict__ w_ih,
        const float* __restrict__ w_hh, unsigned* __restrict__ wt2) {
  __shared__ float t[32][33];
  int jt = blockIdx.x * 32, kt = blockIdx.y * 32;
  int tx = threadIdx.x & 31, ty = threadIdx.x >> 5;   // ty 0..7
#pragma unroll
  for (int i = 0; i < 4; i++) {
    int j = jt + ty + i*8;
    int k = kt + tx;
    float v = (k < 2048) ? w_ih[(size_t)j*2048 + k] : w_hh[(size_t)j*1024 + (k - 2048)];
    t[ty + i*8][tx] = v;                              // t[j_local][k_local]
  }
  __syncthreads();
#pragma unroll
  for (int i = 0; i < 2; i++) {
    int kl2 = ty + i*8;                               // 0..15
    float lo = t[tx][kl2*2], hi = t[tx][kl2*2+1];
    unsigned u = (f2bf(hi) << 16) | f2bf(lo);
    wt2[(size_t)((kt >> 1) + kl2)*4096 + jt + tx] = u;
  }
}

// ---------------- Wc partials: wcp[och][k][d] ----------------
__global__ void k_wc1(const float* __restrict__ up_w, const float* __restrict__ att1w,
                      float* __restrict__ wcp) {
  int k = blockIdx.x;       // 128
  int och = blockIdx.y;     // 8
  int d = threadIdx.x;      // 256
  __shared__ float s[128];
  int o0 = och*128;
  if (d < 128) s[d] = att1w[(size_t)k*2048 + 1024 + o0 + d];
  __syncthreads();
  float acc = 0.0f;
#pragma unroll 8
  for (int oi = 0; oi < 128; oi++) acc += up_w[(size_t)(o0+oi)*256 + d] * s[oi];
  wcp[((size_t)och*128 + k)*256 + d] = acc;
}

__global__ void k_wc2(const float* __restrict__ wcp, float* __restrict__ wc) {
  int k = blockIdx.x, d = threadIdx.x;
  float s = 0.0f;
#pragma unroll
  for (int p = 0; p < 8; p++) s += wcp[((size_t)p*128 + k)*256 + d];
  wc[k*256 + d] = s;
}

// ---------------- bc[k] = sum_o up_b[o] * att1_w[k][1024+o] ----------------
__global__ void k_bc(const float* __restrict__ up_b, const float* __restrict__ att1w,
                     float* __restrict__ bc) {
  int k = blockIdx.x;   // 128 blocks x 64 threads
  int t = threadIdx.x;
  float acc = 0.0f;
#pragma unroll
  for (int i = 0; i < 4; i++) {
    int o = i*256 + t*4;
    float4 a4 = *(const float4*)(att1w + (size_t)k*2048 + 1024 + o);
    float4 b4 = *(const float4*)(up_b + o);
    acc += a4.x*b4.x + a4.y*b4.y + a4.z*b4.z + a4.w*b4.w;
  }
#pragma unroll
  for (int m = 32; m >= 1; m >>= 1) acc += __shfl_xor(acc, m, 64);
  if (t == 0) bc[k] = acc;
}

// ---------------- fp32 GEMM 32x128 tile, BK=32: xa = emb @ wc^T + bc ----------------
__global__ __launch_bounds__(256) void k_gemm32(const float* __restrict__ A,
        const float* __restrict__ W, const float* __restrict__ bias,
        float* __restrict__ C) {
  __shared__ float As[32][33];
  __shared__ float Bs[32][132];
  const int m0 = blockIdx.x * 32;
  const int tid = threadIdx.x;
  const int tx = tid & 15, ty = tid >> 4;
  float acc[2][8];
#pragma unroll
  for (int i = 0; i < 2; i++)
#pragma unroll
    for (int j = 0; j < 8; j++) acc[i][j] = 0.0f;

  for (int kt = 0; kt < 256; kt += 32) {
    {
      int r = tid >> 3;               // 0..31
      int kq = (tid & 7) * 4;         // 0..28
      float4 a4 = *(const float4*)(A + (size_t)(m0 + r)*256 + kt + kq);
      As[kq+0][r] = a4.x; As[kq+1][r] = a4.y; As[kq+2][r] = a4.z; As[kq+3][r] = a4.w;
    }
#pragma unroll
    for (int i = 0; i < 4; i++) {
      int s = tid + i*256;            // 0..1023
      int n = s >> 3;                 // 0..127
      int kq = (s & 7) * 4;
      float4 b4 = *(const float4*)(W + (size_t)n*256 + kt + kq);
      Bs[kq+0][n] = b4.x; Bs[kq+1][n] = b4.y; Bs[kq+2][n] = b4.z; Bs[kq+3][n] = b4.w;
    }
    __syncthreads();
#pragma unroll
    for (int kk = 0; kk < 32; kk++) {
      float a0 = As[kk][ty*2], a1 = As[kk][ty*2+1];
      float4 b0 = *(const float4*)&Bs[kk][tx*4];
      float4 b1 = *(const float4*)&Bs[kk][64 + tx*4];
      float bv[8] = {b0.x,b0.y,b0.z,b0.w,b1.x,b1.y,b1.z,b1.w};
#pragma unroll
      for (int j = 0; j < 8; j++) { acc[0][j] += a0*bv[j]; acc[1][j] += a1*bv[j]; }
    }
    __syncthreads();
  }
#pragma unroll
  for (int i = 0; i < 2; i++) {
    int row = m0 + ty*2 + i;
#pragma unroll
    for (int ch = 0; ch < 2; ch++) {
      int col = ch*64 + tx*4;
      float4 o;
      o.x = acc[i][ch*4+0] + bias[col+0];
      o.y = acc[i][ch*4+1] + bias[col+1];
      o.z = acc[i][ch*4+2] + bias[col+2];
      o.w = acc[i][ch*4+3] + bias[col+3];
      *(float4*)(C + (size_t)row*128 + col) = o;
    }
  }
}

// ---------------- persistent loop kernel (regular launch, flag-array grid barrier) ----------------
__global__ __launch_bounds__(256, 4) void k_loop(
    const unsigned* __restrict__ wt2, const unsigned* __restrict__ embh,
    const float* __restrict__ xa, const float* __restrict__ up_w,
    const float* __restrict__ up_b, const float* __restrict__ b_ih,
    const float* __restrict__ b_hh, const float* __restrict__ att1w,
    const float* __restrict__ att1b, const float* __restrict__ att2w,
    const float* __restrict__ att2b, const float* __restrict__ en_w,
    const float* __restrict__ en_b,
    float* __restrict__ gp, float* __restrict__ P, float* __restrict__ h,
    float* __restrict__ c, float* __restrict__ rap, float* __restrict__ lg,
    float* __restrict__ pp, float* __restrict__ outp, int* __restrict__ bar)
{
  __shared__ __align__(16) float sm[32*XPAD];   // 16.9 KB, reused by every phase
  const int tid = threadIdx.x;
  const int bid = blockIdx.x;
  int ep = 0;

  // flag-array epoch barrier: per-block flag lines (no contention), block 0 scans in
  // parallel, single release word. REL/ACQ at agent scope gives transitive HB.
  auto GBAR = [&]() {
    __syncthreads();
    ++ep;
    if (bid == 0) {
      for (int i = 1 + tid; i < GRID_LOOP; i += 256)
        while (__hip_atomic_load(&bar[i*32], __ATOMIC_ACQUIRE, __HIP_MEMORY_SCOPE_AGENT) < ep)
          __builtin_amdgcn_s_sleep(4);
      __syncthreads();
      if (tid == 0)
        __hip_atomic_store(&bar[GRID_LOOP*32], ep, __ATOMIC_RELEASE, __HIP_MEMORY_SCOPE_AGENT);
    } else {
      if (tid == 0) {
        __hip_atomic_store(&bar[bid*32], ep, __ATOMIC_RELEASE, __HIP_MEMORY_SCOPE_AGENT);
        while (__hip_atomic_load(&bar[GRID_LOOP*32], __ATOMIC_ACQUIRE, __HIP_MEMORY_SCOPE_AGENT) < ep)
          __builtin_amdgcn_s_sleep(4);
      }
      __syncthreads();
    }
  };

  // ---- phase: weighted pool of embh -> pp partials ----
  auto POOL = [&](bool use_lg) {
    for (int wb = bid; wb < 128; wb += GRID_LOOP) {
      int b = wb >> 2, nch = wb & 3;
      float* ws = sm; float* red = sm + 256;
      if (use_lg) {
        float mx = -1e30f;
#pragma unroll
        for (int i = 0; i < 4; i++) mx = fmaxf(mx, lg[b*1024 + tid + i*256]);
        red[tid] = mx; __syncthreads();
        for (int s = 128; s > 0; s >>= 1) { if (tid < s) red[tid] = fmaxf(red[tid], red[tid+s]); __syncthreads(); }
        float m = red[0]; __syncthreads();
        float sum = 0.0f;
#pragma unroll
        for (int i = 0; i < 4; i++) sum += expf(lg[b*1024 + tid + i*256] - m);
        red[tid] = sum; __syncthreads();
        for (int s = 128; s > 0; s >>= 1) { if (tid < s) red[tid] += red[tid+s]; __syncthreads(); }
        float inv = 1.0f / red[0];
        __syncthreads();
        ws[tid] = expf(lg[b*1024 + nch*256 + tid] - m) * inv;
      } else {
        ws[tid] = 1.0f;
      }
      __syncthreads();
      int pu = tid & 127, ng = tid >> 7;
      const unsigned* eb = embh + (size_t)(b*1024 + nch*256 + ng*128)*128 + pu;
      float a0 = 0.0f, a1 = 0.0f;
#pragma unroll 4
      for (int n = 0; n < 128; n++) {
        unsigned u = eb[(size_t)n*128];
        float w = ws[ng*128 + n];
        a0 += w * __uint_as_float(u << 16);
        a1 += w * __uint_as_float(u & 0xffff0000u);
      }
      int p = nch*2 + ng;
      pp[((size_t)p*32 + b)*256 + pu*2]     = a0;
      pp[((size_t)p*32 + b)*256 + pu*2 + 1] = a1;
      __syncthreads();
    }
  };

  // ---- phase: reduce pp -> pe (in LDS) ; P = pe @ up_w^T + up_b ----
  auto PGEMM = [&](float scale) {
    for (int wb = bid; wb < 128; wb += GRID_LOOP) {
      int b = wb >> 2, oc = wb & 3;
      float s = 0.0f;
#pragma unroll
      for (int p = 0; p < 8; p++) s += pp[((size_t)p*32 + b)*256 + tid];
      sm[tid] = s * scale;
      __syncthreads();
      int o = oc*256 + tid;
      const float* wr = up_w + (size_t)o*256;
      float acc = up_b[o];
#pragma unroll 8
      for (int d = 0; d < 256; d += 4) {
        float4 w4 = *(const float4*)(wr + d);
        acc += w4.x*sm[d] + w4.y*sm[d+1] + w4.z*sm[d+2] + w4.w*sm[d+3];
      }
      P[(size_t)b*1024 + o] = acc;
      __syncthreads();
    }
  };

  // ---- phase: gate partials gp[ks][b][j]; 1536 items = 64 jb x 24 ks ----
  auto GATES = [&]() {
    for (int wb = bid; wb < 1536; wb += GRID_LOOP) {
      int jb = wb & 63, ks = wb >> 6;
      int kglob = ks * 128;
      const float* src; int soff;
      if (ks < 8)       { src = P; soff = kglob; }
      else if (ks < 16) { src = h; soff = kglob - 1024; }
      else              { src = h; soff = kglob - 2048; }
#pragma unroll
      for (int i = 0; i < 4; i++) {
        int s = tid + i*256;              // float4 idx 0..1023
        int b = s >> 5, k4 = s & 31;
        *(float4*)&sm[b*XPAD + k4*4] = *(const float4*)(src + b*1024 + soff + k4*4);
      }
      __syncthreads();
      int jg = tid & 15, bg = tid >> 4;   // 16 j-groups x 16 b-groups
      int j0 = jb*64 + jg*4;
      int b0 = bg*2;
      const unsigned* wr = wt2 + (size_t)(ks*64)*4096 + j0;
      const float* xA = sm + b0*XPAD;
      const float* xB = sm + (b0+1)*XPAD;
      float accA[4] = {0,0,0,0}, accB[4] = {0,0,0,0};
#pragma unroll 4
      for (int k2 = 0; k2 < 64; k2++) {
        uint4 u4 = *(const uint4*)(wr + (size_t)k2*4096);
        float w0l = __uint_as_float(u4.x << 16), w0h = __uint_as_float(u4.x & 0xffff0000u);
        float w1l = __uint_as_float(u4.y << 16), w1h = __uint_as_float(u4.y & 0xffff0000u);
        float w2l = __uint_as_float(u4.z << 16), w2h = __uint_as_float(u4.z & 0xffff0000u);
        float w3l = __uint_as_float(u4.w << 16), w3h = __uint_as_float(u4.w & 0xffff0000u);
        float xa0 = xA[k2*2], xa1 = xA[k2*2+1];
        float xb0 = xB[k2*2], xb1 = xB[k2*2+1];
        accA[0] += w0l*xa0 + w0h*xa1; accB[0] += w0l*xb0 + w0h*xb1;
        accA[1] += w1l*xa0 + w1h*xa1; accB[1] += w1l*xb0 + w1h*xb1;
        accA[2] += w2l*xa0 + w2h*xa1; accB[2] += w2l*xb0 + w2h*xb1;
        accA[3] += w3l*xa0 + w3h*xa1; accB[3] += w3l*xb0 + w3h*xb1;
      }
      *(float4*)(gp + ((size_t)ks*32 + b0  )*4096 + j0) = make_float4(accA[0],accA[1],accA[2],accA[3]);
      *(float4*)(gp + ((size_t)ks*32 + b0+1)*4096 + j0) = make_float4(accB[0],accB[1],accB[2],accB[3]);
      __syncthreads();
    }
  };

  // ---- phase: reduce gates + LSTM cell + ra partials per dch ----
  auto LSTM = [&](bool need_ra) {
    for (int wb = bid; wb < 128; wb += GRID_LOOP) {
      int b = wb >> 2, dch = wb & 3;
      int d = dch*256 + tid;
      float gi = b_ih[d]        + b_hh[d];
      float gf = b_ih[1024 + d] + b_hh[1024 + d];
      float gg = b_ih[2048 + d] + b_hh[2048 + d];
      float go = b_ih[3072 + d] + b_hh[3072 + d];
#pragma unroll 4
      for (int ks = 0; ks < 24; ks++) {
        const float* base = gp + ((size_t)ks*32 + b)*4096;
        gi += base[d]; gf += base[1024 + d]; gg += base[2048 + d]; go += base[3072 + d];
      }
      size_t ci = (size_t)b*1024 + d;
      float cn = sigmoidf_(gf)*c[ci] + sigmoidf_(gi)*tanhf(gg);
      c[ci] = cn;
      float hn = sigmoidf_(go)*tanhf(cn);
      h[ci] = hn;
      sm[tid] = hn;
      __syncthreads();
      if (need_ra) {
        int k = tid >> 1, half = tid & 1;
        const float* wr = att1w + (size_t)k*2048 + dch*256 + half*128;
        float acc = 0.0f;
#pragma unroll 8
        for (int i = 0; i < 32; i++) {
          float4 w4 = *(const float4*)(wr + i*4);
          int dl = half*128 + i*4;
          acc += w4.x*sm[dl] + w4.y*sm[dl+1] + w4.z*sm[dl+2] + w4.w*sm[dl+3];
        }
        acc += __shfl_xor(acc, 1, 64);
        if (half == 0) rap[((size_t)dch*32 + b)*128 + k] = acc;
      }
      __syncthreads();
    }
  };

  // ---- phase: logits ----
  auto LOGITS = [&]() {
    for (int wb = bid; wb < 256; wb += GRID_LOOP) {
      int b = wb >> 3, nc = wb & 7;
      float* rb = sm; float* w2 = sm + 128;
      if (tid < 128) {
        float r = rap[(size_t)(0  + b)*128 + tid] + rap[(size_t)(32 + b)*128 + tid]
                + rap[(size_t)(64 + b)*128 + tid] + rap[(size_t)(96 + b)*128 + tid];
        rb[tid] = r + att1b[tid];
        w2[tid] = att2w[tid];
      }
      __syncthreads();
      int n = nc*128 + (tid >> 1);
      int half = (tid & 1) * 64;
      const float* xr = xa + ((size_t)b*1024 + n)*128 + half;
      float acc = 0.0f;
#pragma unroll
      for (int i = 0; i < 16; i++) {
        int kk = i*4;
        float4 v = *(const float4*)(xr + kk);
        int kg = half + kk;
        acc += fmaxf(v.x + rb[kg+0], 0.0f)*w2[kg+0]
             + fmaxf(v.y + rb[kg+1], 0.0f)*w2[kg+1]
             + fmaxf(v.z + rb[kg+2], 0.0f)*w2[kg+2]
             + fmaxf(v.w + rb[kg+3], 0.0f)*w2[kg+3];
      }
      acc += __shfl_xor(acc, 1, 64);
      if ((tid & 1) == 0) lg[(size_t)b*1024 + n] = acc + att2b[0];
      __syncthreads();
    }
  };

  // ---- phase: energy head ----
  auto OUT = [&]() {
    for (int wb = bid; wb < 32; wb += GRID_LOOP) {
      float a = 0.0f;
#pragma unroll
      for (int i = 0; i < 4; i++) { int d = tid + i*256; a += c[(size_t)wb*1024 + d] * en_w[d]; }
      sm[tid] = a; __syncthreads();
      for (int s = 128; s > 0; s >>= 1) { if (tid < s) sm[tid] += sm[tid+s]; __syncthreads(); }
      if (tid == 0) outp[wb] = sm[0] + en_b[0];
      __syncthreads();
    }
  };

  POOL(false);
  GBAR();
  PGEMM(1.0f/1024.0f);
  GBAR();

  for (int step = 0; step < 6; ++step) {
    GATES();
    GBAR();
    LSTM(step < 5);
    GBAR();
    if (step < 5) {      // last step's attention output is unused
      LOGITS();
      GBAR();
      POOL(true);
      GBAR();
      PGEMM(1.0f);
      GBAR();
    }
  }
  OUT();
}

extern "C" void kernel_launch(void* const* d_in, const int* in_sizes, int n_in,
                              void* d_out, int out_size, void* d_ws, size_t ws_size,
                              hipStream_t stream) {
  const int*   x_int  = (const int*)d_in[0];
  const float* x_xyz  = (const float*)d_in[1];
  const float* am     = (const float*)d_in[2];
  const float* el     = (const float*)d_in[3];
  const float* po     = (const float*)d_in[4];
  const float* xyz_w  = (const float*)d_in[5];
  const float* xyz_b  = (const float*)d_in[6];
  const float* up_w   = (const float*)d_in[7];
  const float* up_b   = (const float*)d_in[8];
  const float* w_ih   = (const float*)d_in[9];
  const float* w_hh   = (const float*)d_in[10];
  const float* b_ih   = (const float*)d_in[11];
  const float* b_hh   = (const float*)d_in[12];
  const float* att1_w = (const float*)d_in[13];
  const float* att1_b = (const float*)d_in[14];
  const float* att2_w = (const float*)d_in[15];
  const float* att2_b = (const float*)d_in[16];
  const float* en_w   = (const float*)d_in[17];
  const float* en_b   = (const float*)d_in[18];
  float* out = (float*)d_out;

  char* ws = (char*)d_ws;
  size_t off = 0;
  auto alloc = [&](size_t bytes) { void* p = ws + off; off += (bytes + 255) & ~(size_t)255; return p; };
  float*    emb  = (float*)alloc((size_t)BN*256*4);       // 33.6 MB
  unsigned* embh = (unsigned*)alloc((size_t)BN*128*4);    // 16.8 MB (bf16x2)
  unsigned* wt2  = (unsigned*)alloc((size_t)1536*4096*4); // 25.2 MB
  float*    xa   = (float*)alloc((size_t)BN*128*4);       // 16.8 MB
  float*    wcp  = (float*)alloc((size_t)8*128*256*4);    // 1 MB
  float*    wc   = (float*)alloc((size_t)128*256*4);
  float*    bc   = (float*)alloc((size_t)128*4);
  float*    gp   = (float*)alloc((size_t)24*32*4096*4);   // 12.6 MB
  float*    pp   = (float*)alloc((size_t)8*32*256*4);     // 256 KB
  float*    P    = (float*)alloc((size_t)32*1024*4);
  float*    h    = (float*)alloc((size_t)32*1024*4);
  float*    c    = (float*)alloc((size_t)32*1024*4);
  float*    rap  = (float*)alloc((size_t)4*32*128*4);
  float*    lg   = (float*)alloc((size_t)32*1024*4);
  int*      bar  = (int*)alloc((GRID_LOOP*32 + 64) * 4);  // flags + release word
  (void)ws_size; (void)in_sizes; (void)n_in; (void)out_size;

  k_init<<<128, 256, 0, stream>>>(h, c, bar);
  k_emb<<<BN, 256, 0, stream>>>(x_int, x_xyz, am, el, po, xyz_w, xyz_b, emb, embh);
  k_wt<<<dim3(128, 96), 256, 0, stream>>>(w_ih, w_hh, wt2);
  k_wc1<<<dim3(128, 8), 256, 0, stream>>>(up_w, att1_w, wcp);
  k_wc2<<<128, 256, 0, stream>>>(wcp, wc);
  k_bc<<<128, 64, 0, stream>>>(up_b, att1_w, bc);
  // xa = emb @ wc^T + bc   (M=32768, K=256, N=128)
  k_gemm32<<<BN/32, 256, 0, stream>>>(emb, wc, bc, xa);

  k_loop<<<GRID_LOOP, 256, 0, stream>>>(
      wt2, embh, xa, up_w, up_b, b_ih, b_hh, att1_w, att1_b,
      att2_w, att2_b, en_w, en_b,
      gp, P, h, c, rap, lg, pp, out, bar);
}

// Round 9
// 1064.606 us; speedup vs baseline: 3.2269x; 3.0043x over previous
//
#include <hip/hip_runtime.h>
#include <math.h>

#define BB 32
#define NN 1024
#define BN (BB*NN)
#define GRID_LOOP 512
#define XPAD 132

__device__ __forceinline__ float sigmoidf_(float v) { return 1.0f / (1.0f + expf(-v)); }
__device__ __forceinline__ unsigned f2bf(float f) {           // round-to-nearest-even bf16 bits
  unsigned u = __float_as_uint(f);
  return (u + 0x7fffu + ((u >> 16) & 1u)) >> 16;
}

// ---------------- init: zero h, c, barrier flags ----------------
__global__ void k_init(float* __restrict__ h, float* __restrict__ c, int* __restrict__ bar) {
  int i = blockIdx.x * 256 + threadIdx.x;   // 128 x 256 = 32768
  h[i] = 0.0f; c[i] = 0.0f;
  if (i <= GRID_LOOP*32) bar[i] = 0;        // flags + release word
}

// ---------------- embedding: emb[row][256] fp32 + embh[row][128] packed bf16x2 ----------------
__global__ void k_emb(const int* __restrict__ xint, const float* __restrict__ xyz,
                      const float* __restrict__ am, const float* __restrict__ el,
                      const float* __restrict__ po, const float* __restrict__ xw,
                      const float* __restrict__ xb, float* __restrict__ emb,
                      unsigned* __restrict__ embh) {
  __shared__ float sv[256];
  int row = blockIdx.x;
  int d = threadIdx.x;
  int i0 = xint[row*3+0], i1 = xint[row*3+1], i2 = xint[row*3+2];
  float v;
  if (d < 28)        v = am[i0*28 + d];
  else if (d < 56)   v = el[i1*28 + (d-28)];
  else if (d < 84)   v = po[i2*28 + (d-56)];
  else {
    int o = d - 84;
    float x0 = xyz[row*3+0], x1 = xyz[row*3+1], x2 = xyz[row*3+2];
    v = fmaxf(xw[o*3+0]*x0 + xw[o*3+1]*x1 + xw[o*3+2]*x2 + xb[o], 0.0f);
  }
  emb[(size_t)row*256 + d] = v;
  sv[d] = v;
  __syncthreads();
  if (d < 128) {
    unsigned u = (f2bf(sv[d*2+1]) << 16) | f2bf(sv[d*2]);
    embh[(size_t)row*128 + d] = u;
  }
}

// ---------------- transpose+quantize weights: wt2[k2][j] = pack(bf16 w[2k2][j], bf16 w[2k2+1][j]) ----------------
__global__ __launch_bounds__(256) void k_wt(const float* __restrict__ w_ih,
        const float* __restrict__ w_hh, unsigned* __restrict__ wt2) {
  __shared__ float t[32][33];
  int jt = blockIdx.x * 32, kt = blockIdx.y * 32;
  int tx = threadIdx.x & 31, ty = threadIdx.x >> 5;   // ty 0..7
#pragma unroll
  for (int i = 0; i < 4; i++) {
    int j = jt + ty + i*8;
    int k = kt + tx;
    float v = (k < 2048) ? w_ih[(size_t)j*2048 + k] : w_hh[(size_t)j*1024 + (k - 2048)];
    t[ty + i*8][tx] = v;                              // t[j_local][k_local]
  }
  __syncthreads();
#pragma unroll
  for (int i = 0; i < 2; i++) {
    int kl2 = ty + i*8;                               // 0..15
    float lo = t[tx][kl2*2], hi = t[tx][kl2*2+1];
    unsigned u = (f2bf(hi) << 16) | f2bf(lo);
    wt2[(size_t)((kt >> 1) + kl2)*4096 + jt + tx] = u;
  }
}

// ---------------- Wc partials: wcp[och][k][d] ----------------
__global__ void k_wc1(const float* __restrict__ up_w, const float* __restrict__ att1w,
                      float* __restrict__ wcp) {
  int k = blockIdx.x;       // 128
  int och = blockIdx.y;     // 8
  int d = threadIdx.x;      // 256
  __shared__ float s[128];
  int o0 = och*128;
  if (d < 128) s[d] = att1w[(size_t)k*2048 + 1024 + o0 + d];
  __syncthreads();
  float acc = 0.0f;
#pragma unroll 8
  for (int oi = 0; oi < 128; oi++) acc += up_w[(size_t)(o0+oi)*256 + d] * s[oi];
  wcp[((size_t)och*128 + k)*256 + d] = acc;
}

__global__ void k_wc2(const float* __restrict__ wcp, float* __restrict__ wc) {
  int k = blockIdx.x, d = threadIdx.x;
  float s = 0.0f;
#pragma unroll
  for (int p = 0; p < 8; p++) s += wcp[((size_t)p*128 + k)*256 + d];
  wc[k*256 + d] = s;
}

// ---------------- bc[k] = sum_o up_b[o] * att1_w[k][1024+o] ----------------
__global__ void k_bc(const float* __restrict__ up_b, const float* __restrict__ att1w,
                     float* __restrict__ bc) {
  int k = blockIdx.x;   // 128 blocks x 64 threads
  int t = threadIdx.x;
  float acc = 0.0f;
#pragma unroll
  for (int i = 0; i < 4; i++) {
    int o = i*256 + t*4;
    float4 a4 = *(const float4*)(att1w + (size_t)k*2048 + 1024 + o);
    float4 b4 = *(const float4*)(up_b + o);
    acc += a4.x*b4.x + a4.y*b4.y + a4.z*b4.z + a4.w*b4.w;
  }
#pragma unroll
  for (int m = 32; m >= 1; m >>= 1) acc += __shfl_xor(acc, m, 64);
  if (t == 0) bc[k] = acc;
}

// ---------------- fp32 GEMM 32x128 tile, BK=32: xa = emb @ wc^T + bc ----------------
__global__ __launch_bounds__(256) void k_gemm32(const float* __restrict__ A,
        const float* __restrict__ W, const float* __restrict__ bias,
        float* __restrict__ C) {
  __shared__ float As[32][33];
  __shared__ float Bs[32][132];
  const int m0 = blockIdx.x * 32;
  const int tid = threadIdx.x;
  const int tx = tid & 15, ty = tid >> 4;
  float acc[2][8];
#pragma unroll
  for (int i = 0; i < 2; i++)
#pragma unroll
    for (int j = 0; j < 8; j++) acc[i][j] = 0.0f;

  for (int kt = 0; kt < 256; kt += 32) {
    {
      int r = tid >> 3;               // 0..31
      int kq = (tid & 7) * 4;         // 0..28
      float4 a4 = *(const float4*)(A + (size_t)(m0 + r)*256 + kt + kq);
      As[kq+0][r] = a4.x; As[kq+1][r] = a4.y; As[kq+2][r] = a4.z; As[kq+3][r] = a4.w;
    }
#pragma unroll
    for (int i = 0; i < 4; i++) {
      int s = tid + i*256;            // 0..1023
      int n = s >> 3;                 // 0..127
      int kq = (s & 7) * 4;
      float4 b4 = *(const float4*)(W + (size_t)n*256 + kt + kq);
      Bs[kq+0][n] = b4.x; Bs[kq+1][n] = b4.y; Bs[kq+2][n] = b4.z; Bs[kq+3][n] = b4.w;
    }
    __syncthreads();
#pragma unroll
    for (int kk = 0; kk < 32; kk++) {
      float a0 = As[kk][ty*2], a1 = As[kk][ty*2+1];
      float4 b0 = *(const float4*)&Bs[kk][tx*4];
      float4 b1 = *(const float4*)&Bs[kk][64 + tx*4];
      float bv[8] = {b0.x,b0.y,b0.z,b0.w,b1.x,b1.y,b1.z,b1.w};
#pragma unroll
      for (int j = 0; j < 8; j++) { acc[0][j] += a0*bv[j]; acc[1][j] += a1*bv[j]; }
    }
    __syncthreads();
  }
#pragma unroll
  for (int i = 0; i < 2; i++) {
    int row = m0 + ty*2 + i;
#pragma unroll
    for (int ch = 0; ch < 2; ch++) {
      int col = ch*64 + tx*4;
      float4 o;
      o.x = acc[i][ch*4+0] + bias[col+0];
      o.y = acc[i][ch*4+1] + bias[col+1];
      o.z = acc[i][ch*4+2] + bias[col+2];
      o.w = acc[i][ch*4+3] + bias[col+3];
      *(float4*)(C + (size_t)row*128 + col) = o;
    }
  }
}

// ---------------- persistent loop kernel (regular launch, relaxed-poll grid barrier) ----------------
__global__ __launch_bounds__(256, 4) void k_loop(
    const unsigned* __restrict__ wt2, const unsigned* __restrict__ embh,
    const float* __restrict__ xa, const float* __restrict__ up_w,
    const float* __restrict__ up_b, const float* __restrict__ b_ih,
    const float* __restrict__ b_hh, const float* __restrict__ att1w,
    const float* __restrict__ att1b, const float* __restrict__ att2w,
    const float* __restrict__ att2b, const float* __restrict__ en_w,
    const float* __restrict__ en_b,
    float* __restrict__ gp, float* __restrict__ P, float* __restrict__ h,
    float* __restrict__ c, float* __restrict__ rap, float* __restrict__ lg,
    float* __restrict__ pp, float* __restrict__ outp, int* __restrict__ bar)
{
  __shared__ __align__(16) float sm[32*XPAD];   // 16.9 KB, reused by every phase
  const int tid = threadIdx.x;
  const int bid = blockIdx.x;
  int ep = 0;

  // Epoch barrier, storm-free: RELAXED polls (no per-iteration cache maintenance);
  // ONE release fence (L2 writeback) before the flag store publishes the phase's data;
  // ONE acquire fence (cache invalidate) after the poll succeeds. Round 7's version
  // did acquire semantics on EVERY poll iteration -> ~100us/barrier of L2 maintenance.
  auto GBAR = [&]() {
    __syncthreads();                   // all block stores drained (per-wave vmcnt before barrier)
    ++ep;
    if (bid == 0) {
      if (tid == 0) __builtin_amdgcn_fence(__ATOMIC_RELEASE, "agent");
      for (int i = 1 + tid; i < GRID_LOOP; i += 256)
        while (__hip_atomic_load(&bar[i*32], __ATOMIC_RELAXED, __HIP_MEMORY_SCOPE_AGENT) < ep)
          __builtin_amdgcn_s_sleep(2);
      __syncthreads();
      if (tid == 0) {
        __hip_atomic_store(&bar[GRID_LOOP*32], ep, __ATOMIC_RELAXED, __HIP_MEMORY_SCOPE_AGENT);
        __builtin_amdgcn_fence(__ATOMIC_ACQUIRE, "agent");
      }
      __syncthreads();
    } else {
      if (tid == 0) {
        __builtin_amdgcn_fence(__ATOMIC_RELEASE, "agent");
        __hip_atomic_store(&bar[bid*32], ep, __ATOMIC_RELAXED, __HIP_MEMORY_SCOPE_AGENT);
        while (__hip_atomic_load(&bar[GRID_LOOP*32], __ATOMIC_RELAXED, __HIP_MEMORY_SCOPE_AGENT) < ep)
          __builtin_amdgcn_s_sleep(2);
        __builtin_amdgcn_fence(__ATOMIC_ACQUIRE, "agent");
      }
      __syncthreads();
    }
  };

  // ---- phase: weighted pool of embh -> pp partials ----
  auto POOL = [&](bool use_lg) {
    for (int wb = bid; wb < 128; wb += GRID_LOOP) {
      int b = wb >> 2, nch = wb & 3;
      float* ws = sm; float* red = sm + 256;
      if (use_lg) {
        float mx = -1e30f;
#pragma unroll
        for (int i = 0; i < 4; i++) mx = fmaxf(mx, lg[b*1024 + tid + i*256]);
        red[tid] = mx; __syncthreads();
        for (int s = 128; s > 0; s >>= 1) { if (tid < s) red[tid] = fmaxf(red[tid], red[tid+s]); __syncthreads(); }
        float m = red[0]; __syncthreads();
        float sum = 0.0f;
#pragma unroll
        for (int i = 0; i < 4; i++) sum += expf(lg[b*1024 + tid + i*256] - m);
        red[tid] = sum; __syncthreads();
        for (int s = 128; s > 0; s >>= 1) { if (tid < s) red[tid] += red[tid+s]; __syncthreads(); }
        float inv = 1.0f / red[0];
        __syncthreads();
        ws[tid] = expf(lg[b*1024 + nch*256 + tid] - m) * inv;
      } else {
        ws[tid] = 1.0f;
      }
      __syncthreads();
      int pu = tid & 127, ng = tid >> 7;
      const unsigned* eb = embh + (size_t)(b*1024 + nch*256 + ng*128)*128 + pu;
      float a0 = 0.0f, a1 = 0.0f;
#pragma unroll 4
      for (int n = 0; n < 128; n++) {
        unsigned u = eb[(size_t)n*128];
        float w = ws[ng*128 + n];
        a0 += w * __uint_as_float(u << 16);
        a1 += w * __uint_as_float(u & 0xffff0000u);
      }
      int p = nch*2 + ng;
      pp[((size_t)p*32 + b)*256 + pu*2]     = a0;
      pp[((size_t)p*32 + b)*256 + pu*2 + 1] = a1;
      __syncthreads();
    }
  };

  // ---- phase: reduce pp -> pe (in LDS) ; P = pe @ up_w^T + up_b ----
  auto PGEMM = [&](float scale) {
    for (int wb = bid; wb < 128; wb += GRID_LOOP) {
      int b = wb >> 2, oc = wb & 3;
      float s = 0.0f;
#pragma unroll
      for (int p = 0; p < 8; p++) s += pp[((size_t)p*32 + b)*256 + tid];
      sm[tid] = s * scale;
      __syncthreads();
      int o = oc*256 + tid;
      const float* wr = up_w + (size_t)o*256;
      float acc = up_b[o];
#pragma unroll 8
      for (int d = 0; d < 256; d += 4) {
        float4 w4 = *(const float4*)(wr + d);
        acc += w4.x*sm[d] + w4.y*sm[d+1] + w4.z*sm[d+2] + w4.w*sm[d+3];
      }
      P[(size_t)b*1024 + o] = acc;
      __syncthreads();
    }
  };

  // ---- phase: gate partials gp[ks][b][j]; 1536 items = 64 jb x 24 ks ----
  auto GATES = [&]() {
    for (int wb = bid; wb < 1536; wb += GRID_LOOP) {
      int jb = wb & 63, ks = wb >> 6;
      int kglob = ks * 128;
      const float* src; int soff;
      if (ks < 8)       { src = P; soff = kglob; }
      else if (ks < 16) { src = h; soff = kglob - 1024; }
      else              { src = h; soff = kglob - 2048; }
#pragma unroll
      for (int i = 0; i < 4; i++) {
        int s = tid + i*256;              // float4 idx 0..1023
        int b = s >> 5, k4 = s & 31;
        *(float4*)&sm[b*XPAD + k4*4] = *(const float4*)(src + b*1024 + soff + k4*4);
      }
      __syncthreads();
      int jg = tid & 15, bg = tid >> 4;   // 16 j-groups x 16 b-groups
      int j0 = jb*64 + jg*4;
      int b0 = bg*2;
      const unsigned* wr = wt2 + (size_t)(ks*64)*4096 + j0;
      const float* xA = sm + b0*XPAD;
      const float* xB = sm + (b0+1)*XPAD;
      float accA[4] = {0,0,0,0}, accB[4] = {0,0,0,0};
#pragma unroll 4
      for (int k2 = 0; k2 < 64; k2++) {
        uint4 u4 = *(const uint4*)(wr + (size_t)k2*4096);
        float w0l = __uint_as_float(u4.x << 16), w0h = __uint_as_float(u4.x & 0xffff0000u);
        float w1l = __uint_as_float(u4.y << 16), w1h = __uint_as_float(u4.y & 0xffff0000u);
        float w2l = __uint_as_float(u4.z << 16), w2h = __uint_as_float(u4.z & 0xffff0000u);
        float w3l = __uint_as_float(u4.w << 16), w3h = __uint_as_float(u4.w & 0xffff0000u);
        float xa0 = xA[k2*2], xa1 = xA[k2*2+1];
        float xb0 = xB[k2*2], xb1 = xB[k2*2+1];
        accA[0] += w0l*xa0 + w0h*xa1; accB[0] += w0l*xb0 + w0h*xb1;
        accA[1] += w1l*xa0 + w1h*xa1; accB[1] += w1l*xb0 + w1h*xb1;
        accA[2] += w2l*xa0 + w2h*xa1; accB[2] += w2l*xb0 + w2h*xb1;
        accA[3] += w3l*xa0 + w3h*xa1; accB[3] += w3l*xb0 + w3h*xb1;
      }
      *(float4*)(gp + ((size_t)ks*32 + b0  )*4096 + j0) = make_float4(accA[0],accA[1],accA[2],accA[3]);
      *(float4*)(gp + ((size_t)ks*32 + b0+1)*4096 + j0) = make_float4(accB[0],accB[1],accB[2],accB[3]);
      __syncthreads();
    }
  };

  // ---- phase: reduce gates + LSTM cell + ra partials per dch ----
  auto LSTM = [&](bool need_ra) {
    for (int wb = bid; wb < 128; wb += GRID_LOOP) {
      int b = wb >> 2, dch = wb & 3;
      int d = dch*256 + tid;
      float gi = b_ih[d]        + b_hh[d];
      float gf = b_ih[1024 + d] + b_hh[1024 + d];
      float gg = b_ih[2048 + d] + b_hh[2048 + d];
      float go = b_ih[3072 + d] + b_hh[3072 + d];
#pragma unroll 4
      for (int ks = 0; ks < 24; ks++) {
        const float* base = gp + ((size_t)ks*32 + b)*4096;
        gi += base[d]; gf += base[1024 + d]; gg += base[2048 + d]; go += base[3072 + d];
      }
      size_t ci = (size_t)b*1024 + d;
      float cn = sigmoidf_(gf)*c[ci] + sigmoidf_(gi)*tanhf(gg);
      c[ci] = cn;
      float hn = sigmoidf_(go)*tanhf(cn);
      h[ci] = hn;
      sm[tid] = hn;
      __syncthreads();
      if (need_ra) {
        int k = tid >> 1, half = tid & 1;
        const float* wr = att1w + (size_t)k*2048 + dch*256 + half*128;
        float acc = 0.0f;
#pragma unroll 8
        for (int i = 0; i < 32; i++) {
          float4 w4 = *(const float4*)(wr + i*4);
          int dl = half*128 + i*4;
          acc += w4.x*sm[dl] + w4.y*sm[dl+1] + w4.z*sm[dl+2] + w4.w*sm[dl+3];
        }
        acc += __shfl_xor(acc, 1, 64);
        if (half == 0) rap[((size_t)dch*32 + b)*128 + k] = acc;
      }
      __syncthreads();
    }
  };

  // ---- phase: logits ----
  auto LOGITS = [&]() {
    for (int wb = bid; wb < 256; wb += GRID_LOOP) {
      int b = wb >> 3, nc = wb & 7;
      float* rb = sm; float* w2 = sm + 128;
      if (tid < 128) {
        float r = rap[(size_t)(0  + b)*128 + tid] + rap[(size_t)(32 + b)*128 + tid]
                + rap[(size_t)(64 + b)*128 + tid] + rap[(size_t)(96 + b)*128 + tid];
        rb[tid] = r + att1b[tid];
        w2[tid] = att2w[tid];
      }
      __syncthreads();
      int n = nc*128 + (tid >> 1);
      int half = (tid & 1) * 64;
      const float* xr = xa + ((size_t)b*1024 + n)*128 + half;
      float acc = 0.0f;
#pragma unroll
      for (int i = 0; i < 16; i++) {
        int kk = i*4;
        float4 v = *(const float4*)(xr + kk);
        int kg = half + kk;
        acc += fmaxf(v.x + rb[kg+0], 0.0f)*w2[kg+0]
             + fmaxf(v.y + rb[kg+1], 0.0f)*w2[kg+1]
             + fmaxf(v.z + rb[kg+2], 0.0f)*w2[kg+2]
             + fmaxf(v.w + rb[kg+3], 0.0f)*w2[kg+3];
      }
      acc += __shfl_xor(acc, 1, 64);
      if ((tid & 1) == 0) lg[(size_t)b*1024 + n] = acc + att2b[0];
      __syncthreads();
    }
  };

  // ---- phase: energy head ----
  auto OUT = [&]() {
    for (int wb = bid; wb < 32; wb += GRID_LOOP) {
      float a = 0.0f;
#pragma unroll
      for (int i = 0; i < 4; i++) { int d = tid + i*256; a += c[(size_t)wb*1024 + d] * en_w[d]; }
      sm[tid] = a; __syncthreads();
      for (int s = 128; s > 0; s >>= 1) { if (tid < s) sm[tid] += sm[tid+s]; __syncthreads(); }
      if (tid == 0) outp[wb] = sm[0] + en_b[0];
      __syncthreads();
    }
  };

  POOL(false);
  GBAR();
  PGEMM(1.0f/1024.0f);
  GBAR();

  for (int step = 0; step < 6; ++step) {
    GATES();
    GBAR();
    LSTM(step < 5);
    GBAR();
    if (step < 5) {      // last step's attention output is unused
      LOGITS();
      GBAR();
      POOL(true);
      GBAR();
      PGEMM(1.0f);
      GBAR();
    }
  }
  OUT();
}

extern "C" void kernel_launch(void* const* d_in, const int* in_sizes, int n_in,
                              void* d_out, int out_size, void* d_ws, size_t ws_size,
                              hipStream_t stream) {
  const int*   x_int  = (const int*)d_in[0];
  const float* x_xyz  = (const float*)d_in[1];
  const float* am     = (const float*)d_in[2];
  const float* el     = (const float*)d_in[3];
  const float* po     = (const float*)d_in[4];
  const float* xyz_w  = (const float*)d_in[5];
  const float* xyz_b  = (const float*)d_in[6];
  const float* up_w   = (const float*)d_in[7];
  const float* up_b   = (const float*)d_in[8];
  const float* w_ih   = (const float*)d_in[9];
  const float* w_hh   = (const float*)d_in[10];
  const float* b_ih   = (const float*)d_in[11];
  const float* b_hh   = (const float*)d_in[12];
  const float* att1_w = (const float*)d_in[13];
  const float* att1_b = (const float*)d_in[14];
  const float* att2_w = (const float*)d_in[15];
  const float* att2_b = (const float*)d_in[16];
  const float* en_w   = (const float*)d_in[17];
  const float* en_b   = (const float*)d_in[18];
  float* out = (float*)d_out;

  char* ws = (char*)d_ws;
  size_t off = 0;
  auto alloc = [&](size_t bytes) { void* p = ws + off; off += (bytes + 255) & ~(size_t)255; return p; };
  float*    emb  = (float*)alloc((size_t)BN*256*4);       // 33.6 MB
  unsigned* embh = (unsigned*)alloc((size_t)BN*128*4);    // 16.8 MB (bf16x2)
  unsigned* wt2  = (unsigned*)alloc((size_t)1536*4096*4); // 25.2 MB
  float*    xa   = (float*)alloc((size_t)BN*128*4);       // 16.8 MB
  float*    wcp  = (float*)alloc((size_t)8*128*256*4);    // 1 MB
  float*    wc   = (float*)alloc((size_t)128*256*4);
  float*    bc   = (float*)alloc((size_t)128*4);
  float*    gp   = (float*)alloc((size_t)24*32*4096*4);   // 12.6 MB
  float*    pp   = (float*)alloc((size_t)8*32*256*4);     // 256 KB
  float*    P    = (float*)alloc((size_t)32*1024*4);
  float*    h    = (float*)alloc((size_t)32*1024*4);
  float*    c    = (float*)alloc((size_t)32*1024*4);
  float*    rap  = (float*)alloc((size_t)4*32*128*4);
  float*    lg   = (float*)alloc((size_t)32*1024*4);
  int*      bar  = (int*)alloc((GRID_LOOP*32 + 64) * 4);  // flags + release word
  (void)ws_size; (void)in_sizes; (void)n_in; (void)out_size;

  k_init<<<128, 256, 0, stream>>>(h, c, bar);
  k_emb<<<BN, 256, 0, stream>>>(x_int, x_xyz, am, el, po, xyz_w, xyz_b, emb, embh);
  k_wt<<<dim3(128, 96), 256, 0, stream>>>(w_ih, w_hh, wt2);
  k_wc1<<<dim3(128, 8), 256, 0, stream>>>(up_w, att1_w, wcp);
  k_wc2<<<128, 256, 0, stream>>>(wcp, wc);
  k_bc<<<128, 64, 0, stream>>>(up_b, att1_w, bc);
  // xa = emb @ wc^T + bc   (M=32768, K=256, N=128)
  k_gemm32<<<BN/32, 256, 0, stream>>>(emb, wc, bc, xa);

  k_loop<<<GRID_LOOP, 256, 0, stream>>>(
      wt2, embh, xa, up_w, up_b, b_ih, b_hh, att1_w, att1_b,
      att2_w, att2_b, en_w, en_b,
      gp, P, h, c, rap, lg, pp, out, bar);
}

// Round 10
// 434.639 us; speedup vs baseline: 7.9041x; 2.4494x over previous
//
#include <hip/hip_runtime.h>
#include <math.h>

#define BB 32
#define NN 1024
#define BN (BB*NN)
#define KS 24
#define KCH 128

__device__ __forceinline__ float sigmoidf_(float v) { return 1.0f / (1.0f + expf(-v)); }
__device__ __forceinline__ unsigned f2bf(float f) {           // round-to-nearest-even bf16 bits
  unsigned u = __float_as_uint(f);
  return (u + 0x7fffu + ((u >> 16) & 1u)) >> 16;
}

// ---------------- zero h,c ----------------
__global__ void k_zero(float* __restrict__ h, float* __restrict__ c) {
  int i = blockIdx.x * 256 + threadIdx.x;
  h[i] = 0.0f; c[i] = 0.0f;
}

// ---------------- embedding: emb[row][256] fp32 + embh[row][128] packed bf16x2 ----------------
__global__ void k_emb(const int* __restrict__ xint, const float* __restrict__ xyz,
                      const float* __restrict__ am, const float* __restrict__ el,
                      const float* __restrict__ po, const float* __restrict__ xw,
                      const float* __restrict__ xb, float* __restrict__ emb,
                      unsigned* __restrict__ embh) {
  __shared__ float sv[256];
  int row = blockIdx.x;
  int d = threadIdx.x;
  int i0 = xint[row*3+0], i1 = xint[row*3+1], i2 = xint[row*3+2];
  float v;
  if (d < 28)        v = am[i0*28 + d];
  else if (d < 56)   v = el[i1*28 + (d-28)];
  else if (d < 84)   v = po[i2*28 + (d-56)];
  else {
    int o = d - 84;
    float x0 = xyz[row*3+0], x1 = xyz[row*3+1], x2 = xyz[row*3+2];
    v = fmaxf(xw[o*3+0]*x0 + xw[o*3+1]*x1 + xw[o*3+2]*x2 + xb[o], 0.0f);
  }
  emb[(size_t)row*256 + d] = v;
  sv[d] = v;
  __syncthreads();
  if (d < 128) {
    unsigned u = (f2bf(sv[d*2+1]) << 16) | f2bf(sv[d*2]);
    embh[(size_t)row*128 + d] = u;
  }
}

// ---------------- transpose+quantize weights: wt2[k2][j] = pack(bf16 w[2k2][j], bf16 w[2k2+1][j]) ----------------
__global__ __launch_bounds__(256) void k_wt(const float* __restrict__ w_ih,
        const float* __restrict__ w_hh, unsigned* __restrict__ wt2) {
  __shared__ float t[32][33];
  int jt = blockIdx.x * 32, kt = blockIdx.y * 32;
  int tx = threadIdx.x & 31, ty = threadIdx.x >> 5;   // ty 0..7
#pragma unroll
  for (int i = 0; i < 4; i++) {
    int j = jt + ty + i*8;
    int k = kt + tx;
    float v = (k < 2048) ? w_ih[(size_t)j*2048 + k] : w_hh[(size_t)j*1024 + (k - 2048)];
    t[ty + i*8][tx] = v;                              // t[j_local][k_local]
  }
  __syncthreads();
#pragma unroll
  for (int i = 0; i < 2; i++) {
    int kl2 = ty + i*8;                               // 0..15
    float lo = t[tx][kl2*2], hi = t[tx][kl2*2+1];
    unsigned u = (f2bf(hi) << 16) | f2bf(lo);
    wt2[(size_t)((kt >> 1) + kl2)*4096 + jt + tx] = u;
  }
}

// ---------------- Wc partials: wcp[och][k][d] ----------------
__global__ void k_wc1(const float* __restrict__ up_w, const float* __restrict__ att1w,
                      float* __restrict__ wcp) {
  int k = blockIdx.x;       // 128
  int och = blockIdx.y;     // 8
  int d = threadIdx.x;      // 256
  __shared__ float s[128];
  int o0 = och*128;
  if (d < 128) s[d] = att1w[(size_t)k*2048 + 1024 + o0 + d];
  __syncthreads();
  float acc = 0.0f;
#pragma unroll 8
  for (int oi = 0; oi < 128; oi++) acc += up_w[(size_t)(o0+oi)*256 + d] * s[oi];
  wcp[((size_t)och*128 + k)*256 + d] = acc;
}

__global__ void k_wc2(const float* __restrict__ wcp, float* __restrict__ wc) {
  int k = blockIdx.x, d = threadIdx.x;
  float s = 0.0f;
#pragma unroll
  for (int p = 0; p < 8; p++) s += wcp[((size_t)p*128 + k)*256 + d];
  wc[k*256 + d] = s;
}

// ---------------- bc[k] = sum_o up_b[o] * att1_w[k][1024+o] ----------------
__global__ void k_bc(const float* __restrict__ up_b, const float* __restrict__ att1w,
                     float* __restrict__ bc) {
  int k = blockIdx.x;   // 128 blocks x 64 threads
  int t = threadIdx.x;
  float acc = 0.0f;
#pragma unroll
  for (int i = 0; i < 4; i++) {
    int o = i*256 + t*4;
    float4 a4 = *(const float4*)(att1w + (size_t)k*2048 + 1024 + o);
    float4 b4 = *(const float4*)(up_b + o);
    acc += a4.x*b4.x + a4.y*b4.y + a4.z*b4.z + a4.w*b4.w;
  }
#pragma unroll
  for (int m = 32; m >= 1; m >>= 1) acc += __shfl_xor(acc, m, 64);
  if (t == 0) bc[k] = acc;
}

// ---------------- fp32 GEMM 32x128 tile, BK=32: xa = emb @ wc^T + bc (1024 blocks) ----------------
__global__ __launch_bounds__(256) void k_gemm32(const float* __restrict__ A,
        const float* __restrict__ W, const float* __restrict__ bias,
        float* __restrict__ C) {
  __shared__ float As[32][33];
  __shared__ float Bs[32][132];
  const int m0 = blockIdx.x * 32;
  const int tid = threadIdx.x;
  const int tx = tid & 15, ty = tid >> 4;
  float acc[2][8];
#pragma unroll
  for (int i = 0; i < 2; i++)
#pragma unroll
    for (int j = 0; j < 8; j++) acc[i][j] = 0.0f;

  for (int kt = 0; kt < 256; kt += 32) {
    {
      int r = tid >> 3;               // 0..31
      int kq = (tid & 7) * 4;         // 0..28
      float4 a4 = *(const float4*)(A + (size_t)(m0 + r)*256 + kt + kq);
      As[kq+0][r] = a4.x; As[kq+1][r] = a4.y; As[kq+2][r] = a4.z; As[kq+3][r] = a4.w;
    }
#pragma unroll
    for (int i = 0; i < 4; i++) {
      int s = tid + i*256;            // 0..1023
      int n = s >> 3;                 // 0..127
      int kq = (s & 7) * 4;
      float4 b4 = *(const float4*)(W + (size_t)n*256 + kt + kq);
      Bs[kq+0][n] = b4.x; Bs[kq+1][n] = b4.y; Bs[kq+2][n] = b4.z; Bs[kq+3][n] = b4.w;
    }
    __syncthreads();
#pragma unroll
    for (int kk = 0; kk < 32; kk++) {
      float a0 = As[kk][ty*2], a1 = As[kk][ty*2+1];
      float4 b0 = *(const float4*)&Bs[kk][tx*4];
      float4 b1 = *(const float4*)&Bs[kk][64 + tx*4];
      float bv[8] = {b0.x,b0.y,b0.z,b0.w,b1.x,b1.y,b1.z,b1.w};
#pragma unroll
      for (int j = 0; j < 8; j++) { acc[0][j] += a0*bv[j]; acc[1][j] += a1*bv[j]; }
    }
    __syncthreads();
  }
#pragma unroll
  for (int i = 0; i < 2; i++) {
    int row = m0 + ty*2 + i;
#pragma unroll
    for (int ch = 0; ch < 2; ch++) {
      int col = ch*64 + tx*4;
      float4 o;
      o.x = acc[i][ch*4+0] + bias[col+0];
      o.y = acc[i][ch*4+1] + bias[col+1];
      o.z = acc[i][ch*4+2] + bias[col+2];
      o.w = acc[i][ch*4+3] + bias[col+3];
      *(float4*)(C + (size_t)row*128 + col) = o;
    }
  }
}

// ---------------- gates partials over bf16-packed transposed weights ----------------
// grid (32 jb, 24 ks); block 256; each block: 128 j x 32 b for one 128-k slice
__global__ __launch_bounds__(256) void k_gates(const float* __restrict__ P, const float* __restrict__ h,
        const unsigned* __restrict__ wt2, float* __restrict__ gp) {
  __shared__ float Xs[32][KCH];     // 16 KB
  int jb = blockIdx.x;              // 0..31
  int ks = blockIdx.y;              // 0..23
  int tid = threadIdx.x;
  int kglob = ks * KCH;
  const float* src; int soff;
  if (ks < 8)       { src = P; soff = kglob; }
  else if (ks < 16) { src = h; soff = kglob - 1024; }
  else              { src = h; soff = kglob - 2048; }
#pragma unroll
  for (int i = 0; i < 4; i++) {
    int s = tid + i*256;            // float4 idx 0..1023
    int b = s >> 5, k4 = s & 31;
    *(float4*)&Xs[b][k4*4] = *(const float4*)(src + b*1024 + soff + k4*4);
  }
  __syncthreads();

  int jg = tid & 31, bg = tid >> 5;        // 32 j-groups x 8 b-groups
  int j0 = jb*128 + jg*4;
  int b0 = bg*4;
  const unsigned* wr = wt2 + (size_t)(ks*64)*4096 + j0;
  float acc[4][4];
#pragma unroll
  for (int i = 0; i < 4; i++)
#pragma unroll
    for (int j = 0; j < 4; j++) acc[i][j] = 0.0f;

  for (int k2 = 0; k2 < KCH/2; k2++) {
    uint4 u4 = *(const uint4*)(wr + (size_t)k2*4096);
    float wlo[4], whi[4];
    wlo[0] = __uint_as_float(u4.x << 16); whi[0] = __uint_as_float(u4.x & 0xffff0000u);
    wlo[1] = __uint_as_float(u4.y << 16); whi[1] = __uint_as_float(u4.y & 0xffff0000u);
    wlo[2] = __uint_as_float(u4.z << 16); whi[2] = __uint_as_float(u4.z & 0xffff0000u);
    wlo[3] = __uint_as_float(u4.w << 16); whi[3] = __uint_as_float(u4.w & 0xffff0000u);
    int k = k2*2;
#pragma unroll
    for (int bi = 0; bi < 4; bi++) {
      float x0 = Xs[b0+bi][k], x1 = Xs[b0+bi][k+1];
#pragma unroll
      for (int ji = 0; ji < 4; ji++) acc[ji][bi] += wlo[ji]*x0 + whi[ji]*x1;
    }
  }
#pragma unroll
  for (int bi = 0; bi < 4; bi++) {
    float4 v = make_float4(acc[0][bi], acc[1][bi], acc[2][bi], acc[3][bi]);
    *(float4*)(gp + ((size_t)ks*32 + b0 + bi)*4096 + j0) = v;
  }
}

// ---------------- reduce gates + LSTM cell + ra partials per dch (128 blocks) ----------------
__global__ __launch_bounds__(256) void k_lstm_rap(const float* __restrict__ gp,
        const float* __restrict__ b_ih, const float* __restrict__ b_hh,
        float* __restrict__ c, float* __restrict__ h,
        const float* __restrict__ att1w, float* __restrict__ rap, int need_ra) {
  int wb = blockIdx.x;             // 128 = b(32) x dch(4)
  int b = wb >> 2, dch = wb & 3;
  int tid = threadIdx.x;
  int d = dch*256 + tid;
  __shared__ float hs[256];
  float gi = b_ih[d]        + b_hh[d];
  float gf = b_ih[1024 + d] + b_hh[1024 + d];
  float gg = b_ih[2048 + d] + b_hh[2048 + d];
  float go = b_ih[3072 + d] + b_hh[3072 + d];
#pragma unroll 4
  for (int ks = 0; ks < KS; ks++) {
    const float* base = gp + ((size_t)ks*32 + b)*4096;
    gi += base[d]; gf += base[1024 + d]; gg += base[2048 + d]; go += base[3072 + d];
  }
  size_t ci = (size_t)b*1024 + d;
  float cn = sigmoidf_(gf)*c[ci] + sigmoidf_(gi)*tanhf(gg);
  c[ci] = cn;
  float hn = sigmoidf_(go)*tanhf(cn);
  h[ci] = hn;
  hs[tid] = hn;
  __syncthreads();
  if (need_ra) {
    int k = tid >> 1, half = tid & 1;
    const float* wr = att1w + (size_t)k*2048 + dch*256 + half*128;
    float acc = 0.0f;
#pragma unroll 8
    for (int i = 0; i < 32; i++) {
      float4 w4 = *(const float4*)(wr + i*4);
      int dl = half*128 + i*4;
      acc += w4.x*hs[dl] + w4.y*hs[dl+1] + w4.z*hs[dl+2] + w4.w*hs[dl+3];
    }
    acc += __shfl_xor(acc, 1, 64);
    if (half == 0) rap[((size_t)dch*32 + b)*128 + k] = acc;
  }
}

// ---------------- logits[b][n] from xa + rap partials, grid (32 b, 8 nc) ----------------
__global__ __launch_bounds__(256) void k_logits(const float* __restrict__ xa,
        const float* __restrict__ rap, const float* __restrict__ att1b,
        const float* __restrict__ att2w, const float* __restrict__ att2b,
        float* __restrict__ lg) {
  int b = blockIdx.x, nc = blockIdx.y;
  int t = threadIdx.x;
  __shared__ float rb[128], w2[128];
  if (t < 128) {
    float r = rap[(size_t)(0  + b)*128 + t] + rap[(size_t)(32 + b)*128 + t]
            + rap[(size_t)(64 + b)*128 + t] + rap[(size_t)(96 + b)*128 + t];
    rb[t] = r + att1b[t];
    w2[t] = att2w[t];
  }
  __syncthreads();
  int n = nc*128 + (t >> 1);
  int half = (t & 1) * 64;
  const float* xr = xa + ((size_t)b*1024 + n)*128 + half;
  float acc = 0.0f;
#pragma unroll
  for (int i = 0; i < 16; i++) {
    int kk = i*4;
    float4 v = *(const float4*)(xr + kk);
    int kg = half + kk;
    acc += fmaxf(v.x + rb[kg+0], 0.0f)*w2[kg+0]
         + fmaxf(v.y + rb[kg+1], 0.0f)*w2[kg+1]
         + fmaxf(v.z + rb[kg+2], 0.0f)*w2[kg+2]
         + fmaxf(v.w + rb[kg+3], 0.0f)*w2[kg+3];
  }
  acc += __shfl_xor(acc, 1, 64);
  if ((t & 1) == 0) lg[(size_t)b*1024 + n] = acc + att2b[0];
}

// ---------------- pooled bf16-emb partials with in-block softmax; lg==nullptr -> uniform ----------------
// 128 blocks = b(32) x nch(4); each block covers 256 n (two 128-n groups via ng)
__global__ __launch_bounds__(256) void k_poolemb(const unsigned* __restrict__ embh,
        const float* __restrict__ lg, float* __restrict__ pp) {
  int wb = blockIdx.x;
  int b = wb >> 2, nch = wb & 3;
  int tid = threadIdx.x;
  __shared__ float ws[256];
  __shared__ float red[256];
  if (lg) {
    float mx = -1e30f;
#pragma unroll
    for (int i = 0; i < 4; i++) mx = fmaxf(mx, lg[b*1024 + tid + i*256]);
    red[tid] = mx; __syncthreads();
    for (int s = 128; s > 0; s >>= 1) { if (tid < s) red[tid] = fmaxf(red[tid], red[tid+s]); __syncthreads(); }
    float m = red[0]; __syncthreads();
    float sum = 0.0f;
#pragma unroll
    for (int i = 0; i < 4; i++) sum += expf(lg[b*1024 + tid + i*256] - m);
    red[tid] = sum; __syncthreads();
    for (int s = 128; s > 0; s >>= 1) { if (tid < s) red[tid] += red[tid+s]; __syncthreads(); }
    float inv = 1.0f / red[0];
    __syncthreads();
    ws[tid] = expf(lg[b*1024 + nch*256 + tid] - m) * inv;
  } else {
    ws[tid] = 1.0f;
  }
  __syncthreads();
  int pu = tid & 127, ng = tid >> 7;
  const unsigned* eb = embh + (size_t)(b*1024 + nch*256 + ng*128)*128 + pu;
  float a0 = 0.0f, a1 = 0.0f;
#pragma unroll 4
  for (int n = 0; n < 128; n++) {
    unsigned u = eb[(size_t)n*128];
    float w = ws[ng*128 + n];
    a0 += w * __uint_as_float(u << 16);
    a1 += w * __uint_as_float(u & 0xffff0000u);
  }
  int p = nch*2 + ng;
  pp[((size_t)p*32 + b)*256 + pu*2]     = a0;
  pp[((size_t)p*32 + b)*256 + pu*2 + 1] = a1;
}

// ---------------- fused: pe = scale * sum_p pp ; P[b][o] = pe[b].up_w[o] + up_b[o] ----------------
__global__ __launch_bounds__(256) void k_pool_pgemm(const float* __restrict__ pp,
        const float* __restrict__ up_w, const float* __restrict__ up_b,
        float* __restrict__ Pout, float scale) {
  int wb = blockIdx.x;             // 128 = b(32) x oc(4)
  int b = wb >> 2, oc = wb & 3;
  int tid = threadIdx.x;
  __shared__ float pe[256];
  float s = 0.0f;
#pragma unroll
  for (int p = 0; p < 8; p++) s += pp[((size_t)p*32 + b)*256 + tid];
  pe[tid] = s * scale;
  __syncthreads();
  int o = oc*256 + tid;
  const float* wr = up_w + (size_t)o*256;
  float acc = up_b[o];
#pragma unroll 8
  for (int d = 0; d < 256; d += 4) {
    float4 w4 = *(const float4*)(wr + d);
    acc += w4.x*pe[d] + w4.y*pe[d+1] + w4.z*pe[d+2] + w4.w*pe[d+3];
  }
  Pout[(size_t)b*1024 + o] = acc;
}

// ---------------- final energy ----------------
__global__ void k_out(const float* __restrict__ c, const float* __restrict__ ew,
                      const float* __restrict__ eb, float* __restrict__ out) {
  int b = blockIdx.x, t = threadIdx.x;   // 32 x 64
  float acc = 0.0f;
  for (int d = t; d < 1024; d += 64) acc += c[b*1024 + d] * ew[d];
  for (int off = 32; off > 0; off >>= 1) acc += __shfl_down(acc, off, 64);
  if (t == 0) out[b] = acc + eb[0];
}

extern "C" void kernel_launch(void* const* d_in, const int* in_sizes, int n_in,
                              void* d_out, int out_size, void* d_ws, size_t ws_size,
                              hipStream_t stream) {
  const int*   x_int  = (const int*)d_in[0];
  const float* x_xyz  = (const float*)d_in[1];
  const float* am     = (const float*)d_in[2];
  const float* el     = (const float*)d_in[3];
  const float* po     = (const float*)d_in[4];
  const float* xyz_w  = (const float*)d_in[5];
  const float* xyz_b  = (const float*)d_in[6];
  const float* up_w   = (const float*)d_in[7];
  const float* up_b   = (const float*)d_in[8];
  const float* w_ih   = (const float*)d_in[9];
  const float* w_hh   = (const float*)d_in[10];
  const float* b_ih   = (const float*)d_in[11];
  const float* b_hh   = (const float*)d_in[12];
  const float* att1_w = (const float*)d_in[13];
  const float* att1_b = (const float*)d_in[14];
  const float* att2_w = (const float*)d_in[15];
  const float* att2_b = (const float*)d_in[16];
  const float* en_w   = (const float*)d_in[17];
  const float* en_b   = (const float*)d_in[18];
  float* out = (float*)d_out;

  char* ws = (char*)d_ws;
  size_t off = 0;
  auto alloc = [&](size_t bytes) { void* p = ws + off; off += (bytes + 255) & ~(size_t)255; return p; };
  float*    emb  = (float*)alloc((size_t)BN*256*4);       // 33.6 MB
  unsigned* embh = (unsigned*)alloc((size_t)BN*128*4);    // 16.8 MB (bf16x2)
  unsigned* wt2  = (unsigned*)alloc((size_t)1536*4096*4); // 25.2 MB
  float*    xa   = (float*)alloc((size_t)BN*128*4);       // 16.8 MB
  float*    wcp  = (float*)alloc((size_t)8*128*256*4);    // 1 MB
  float*    wc   = (float*)alloc((size_t)128*256*4);
  float*    bc   = (float*)alloc((size_t)128*4);
  float*    gp   = (float*)alloc((size_t)KS*32*4096*4);   // 12.6 MB
  float*    pp   = (float*)alloc((size_t)8*32*256*4);     // 256 KB
  float*    P    = (float*)alloc((size_t)32*1024*4);
  float*    h    = (float*)alloc((size_t)32*1024*4);
  float*    c    = (float*)alloc((size_t)32*1024*4);
  float*    rap  = (float*)alloc((size_t)4*32*128*4);
  float*    lg   = (float*)alloc((size_t)32*1024*4);
  (void)ws_size; (void)in_sizes; (void)n_in; (void)out_size;

  k_zero<<<128, 256, 0, stream>>>(h, c);
  k_emb<<<BN, 256, 0, stream>>>(x_int, x_xyz, am, el, po, xyz_w, xyz_b, emb, embh);
  k_wt<<<dim3(128, 96), 256, 0, stream>>>(w_ih, w_hh, wt2);
  k_wc1<<<dim3(128, 8), 256, 0, stream>>>(up_w, att1_w, wcp);
  k_wc2<<<128, 256, 0, stream>>>(wcp, wc);
  k_bc<<<128, 64, 0, stream>>>(up_b, att1_w, bc);
  // xa = emb @ wc^T + bc   (M=32768, K=256, N=128)
  k_gemm32<<<BN/32, 256, 0, stream>>>(emb, wc, bc, xa);
  // P0 = mean path (uniform weights, scale 1/1024 in pgemm)
  k_poolemb<<<128, 256, 0, stream>>>(embh, nullptr, pp);
  k_pool_pgemm<<<128, 256, 0, stream>>>(pp, up_w, up_b, P, 1.0f/1024.0f);

  for (int step = 0; step < 6; step++) {
    k_gates<<<dim3(32, KS), 256, 0, stream>>>(P, h, wt2, gp);
    k_lstm_rap<<<128, 256, 0, stream>>>(gp, b_ih, b_hh, c, h, att1_w, rap, step < 5 ? 1 : 0);
    if (step < 5) {  // last step's attention output is unused
      k_logits<<<dim3(32, 8), 256, 0, stream>>>(xa, rap, att1_b, att2_w, att2_b, lg);
      k_poolemb<<<128, 256, 0, stream>>>(embh, lg, pp);
      k_pool_pgemm<<<128, 256, 0, stream>>>(pp, up_w, up_b, P, 1.0f);
    }
  }
  k_out<<<32, 64, 0, stream>>>(c, en_w, en_b, out);
}